// Round 5
// baseline (869.989 us; speedup 1.0000x reference)
//
#include <hip/hip_runtime.h>
#include <hip/hip_bf16.h>

// GAT 3-layer pipeline. fp32 inputs/outputs; bf16 MFMA interior.
// N=50000, E=500000; layers: 384->4x64 (concat 256), 256->4x64, 256->1x128.

typedef __bf16 bf16x8_t __attribute__((ext_vector_type(8)));
typedef float  fx4      __attribute__((ext_vector_type(4)));

__device__ __forceinline__ float u2f(unsigned short u) {
    return __uint_as_float(((unsigned)u) << 16);   // exact bf16 -> fp32
}
__device__ __forceinline__ unsigned short f2u(float f) {  // RN fp32 -> bf16 bits
    unsigned b = __float_as_uint(f);
    unsigned rounded = b + 0x7FFF + ((b >> 16) & 1);
    if (((b >> 23) & 0xFF) == 0xFF) rounded = b;
    return (unsigned short)(rounded >> 16);
}

// ---------------- fp32 -> bf16 bulk convert ----------------
__global__ void f32_to_bf16_k(const float* __restrict__ src, unsigned short* __restrict__ dst,
                              long n) {
    long i = (long)blockIdx.x * 256 + threadIdx.x;
    const long stride = (long)gridDim.x * 256;
    for (; i < n; i += stride) dst[i] = f2u(src[i]);
}

// transpose+convert: W fp32 [K,N] -> Wt bf16 [N,K]
__global__ void transpose_conv_k(const float* __restrict__ W, unsigned short* __restrict__ Wt,
                                 int K, int N) {
    int idx = blockIdx.x * 256 + threadIdx.x;
    if (idx >= K * N) return;
    int k = idx / N, n = idx - k * N;
    Wt[(size_t)n * K + k] = f2u(W[idx]);
}

// fallback fill (fp32)
__global__ void fill_const_f32_k(float* __restrict__ out, long n, float v) {
    long i = (long)blockIdx.x * 256 + threadIdx.x;
    const long stride = (long)gridDim.x * 256;
    for (; i < n; i += stride) out[i] = v;
}

// ---------------- CSR build (grouped by row = aggregation target) ----------------
__global__ void count_k(const int* __restrict__ row, int* __restrict__ cnt, int E, int Nn) {
    int e = blockIdx.x * 256 + threadIdx.x;
    if (e >= E) return;
    int r = row[e];
    if ((unsigned)r < (unsigned)Nn) atomicAdd(&cnt[r], 1);
}

__global__ void exscan_k(const int* __restrict__ cnt, int* __restrict__ rowptr,
                         int* __restrict__ cursor, int N) {
    __shared__ int sm[1024];
    __shared__ int carry;
    int tid = threadIdx.x;
    if (tid == 0) { carry = 0; rowptr[0] = 0; }
    __syncthreads();
    for (int base = 0; base < N; base += 1024) {
        int i = base + tid;
        int v = (i < N) ? cnt[i] : 0;
        sm[tid] = v;
        __syncthreads();
        for (int off2 = 1; off2 < 1024; off2 <<= 1) {
            int t = (tid >= off2) ? sm[tid - off2] : 0;
            __syncthreads();
            sm[tid] += t;
            __syncthreads();
        }
        int inc = sm[tid] + carry;
        if (i < N) { rowptr[i + 1] = inc; cursor[i] = inc - v; }
        __syncthreads();
        if (tid == 1023) carry = inc;
        __syncthreads();
    }
}

__global__ void fill_k(const int* __restrict__ row, const int* __restrict__ col,
                       const float* __restrict__ ew,
                       int* __restrict__ cursor, int* __restrict__ ccol,
                       float* __restrict__ cew, int E, int Nn) {
    int e = blockIdx.x * 256 + threadIdx.x;
    if (e >= E) return;
    int r = row[e];
    if ((unsigned)r >= (unsigned)Nn) return;
    int slot = atomicAdd(&cursor[r], 1);
    int c = col[e];
    if ((unsigned)c >= (unsigned)Nn) c = 0;
    ccol[slot] = c;
    cew[slot] = ew[e];
}

// ---------------- bf16 MFMA GEMM: C[M,Ncol] = A[M,K] * Bt[Ncol,K]^T, bf16 out ----------------
#define LSTR 40  // LDS row stride in bf16 units (32 + 8 pad)
__global__ __launch_bounds__(256) void gemm_bf16(const unsigned short* __restrict__ A,
                                                 const unsigned short* __restrict__ Bt,
                                                 unsigned short* __restrict__ C,
                                                 int M, int Ncol, int K) {
    __shared__ unsigned short As[128 * LSTR];
    __shared__ unsigned short Bs[128 * LSTR];
    const int t = threadIdx.x;
    const int lane = t & 63;
    const int wave = t >> 6;
    const int quad = lane >> 4, l16 = lane & 15;
    const int row0 = blockIdx.y * 128, col0 = blockIdx.x * 128;
    const int wr = (wave >> 1) * 64, wc = (wave & 1) * 64;
    const int sr = t >> 2, ss = (t & 3) * 8;
    fx4 acc[4][4] = {};
    for (int k0 = 0; k0 < K; k0 += 32) {
#pragma unroll
        for (int rr = 0; rr < 2; rr++) {
            int r = sr + rr * 64;
            uint4 av = make_uint4(0, 0, 0, 0);
            int gr = row0 + r;
            if (gr < M) av = *(const uint4*)(A + (size_t)gr * K + k0 + ss);
            *(uint4*)(As + r * LSTR + ss) = av;
            uint4 bv = *(const uint4*)(Bt + (size_t)(col0 + r) * K + k0 + ss);
            *(uint4*)(Bs + r * LSTR + ss) = bv;
        }
        __syncthreads();
        bf16x8_t af[4], bfr[4];
#pragma unroll
        for (int i = 0; i < 4; i++) {
            af[i]  = *(const bf16x8_t*)(As + (wr + i * 16 + l16) * LSTR + quad * 8);
            bfr[i] = *(const bf16x8_t*)(Bs + (wc + i * 16 + l16) * LSTR + quad * 8);
        }
#pragma unroll
        for (int i = 0; i < 4; i++)
#pragma unroll
            for (int j = 0; j < 4; j++)
                acc[i][j] = __builtin_amdgcn_mfma_f32_16x16x32_bf16(af[i], bfr[j], acc[i][j], 0, 0, 0);
        __syncthreads();
    }
    // C/D layout: col = lane&15, row = quad*4 + reg  (m89-verified)
#pragma unroll
    for (int i = 0; i < 4; i++) {
        int rb = row0 + wr + i * 16 + quad * 4;
#pragma unroll
        for (int j = 0; j < 4; j++) {
            int c = col0 + wc + j * 16 + l16;
#pragma unroll
            for (int r = 0; r < 4; r++) {
                int gr = rb + r;
                if (gr < M) C[(size_t)gr * Ncol + c] = f2u(acc[i][j][r]);
            }
        }
    }
}

// ---------------- per-node attention scores (fp32 params, bf16 h) ----------------
template <int CPL, int LPH, int H>
__global__ __launch_bounds__(256) void scores_k(const unsigned short* __restrict__ hb,
                                                const float* __restrict__ asrc,
                                                const float* __restrict__ adst,
                                                float* __restrict__ ssrc, float* __restrict__ sdst,
                                                int N) {
    int node = blockIdx.x * 4 + (threadIdx.x >> 6);
    if (node >= N) return;
    int lane = threadIdx.x & 63;
    const int D = CPL * 64;
    const unsigned short* hp = hb + (size_t)node * D + lane * CPL;
    float s1 = 0.f, s2 = 0.f;
#pragma unroll
    for (int i = 0; i < CPL; i++) {
        float h = u2f(hp[i]);
        s1 += h * asrc[lane * CPL + i];
        s2 += h * adst[lane * CPL + i];
    }
#pragma unroll
    for (int m = 1; m < LPH; m <<= 1) {
        s1 += __shfl_xor(s1, m);
        s2 += __shfl_xor(s2, m);
    }
    if ((lane & (LPH - 1)) == 0) {
        ssrc[(size_t)node * H + lane / LPH] = s1;
        sdst[(size_t)node * H + lane / LPH] = s2;
    }
}

// ---------------- per-edge softmax denominator ----------------
template <int H>
__global__ void denom_k(const int* __restrict__ row, const int* __restrict__ col,
                        const float* __restrict__ ew,
                        const float* __restrict__ ssrc, const float* __restrict__ sdst,
                        float* __restrict__ denom, int E, int Nn) {
    int e = blockIdx.x * 256 + threadIdx.x;
    if (e >= E) return;
    int r = row[e], c = col[e];
    if ((unsigned)r >= (unsigned)Nn || (unsigned)c >= (unsigned)Nn) return;
    float w = ew[e];
#pragma unroll
    for (int h = 0; h < H; h++) {
        float s = ssrc[(size_t)r * H + h] + sdst[(size_t)c * H + h];
        s = (s > 0.f) ? s : 0.2f * s;                    // leaky_relu 0.2
        float ae = __expf(fminf(s * w, 60.f));
        atomicAdd(&denom[(size_t)c * H + h], ae);
    }
}

// ---------------- fused: CSR aggregate (recomputed alpha) + bias + LN + (ELU) ----------------
template <int CPL, int H, bool DOELU, bool F32OUT>
__global__ __launch_bounds__(256) void agg_ln_k(const unsigned short* __restrict__ hb,
                                                const float* __restrict__ ssrc,
                                                const float* __restrict__ sdst,
                                                const float* __restrict__ denom,
                                                const int* __restrict__ rowptr,
                                                const int* __restrict__ ccol,
                                                const float* __restrict__ cew,
                                                const float* __restrict__ bias,
                                                const float* __restrict__ gamma,
                                                const float* __restrict__ beta,
                                                void* __restrict__ outv, int N, int E) {
    int node = blockIdx.x * 4 + (threadIdx.x >> 6);
    if (node >= N) return;
    int lane = threadIdx.x & 63;
    const int D = CPL * 64, C = D / H;
    const int head = (lane * CPL) / C;
    const float sn = ssrc[(size_t)node * H + head];      // uniform within head-group
    float acc[CPL] = {};
    int kbeg = rowptr[node], kend = rowptr[node + 1];
    if (kbeg < 0) kbeg = 0;
    if (kend > E) kend = E;
    for (int k = kbeg; k < kend; k++) {
        int c = ccol[k];
        float we = cew[k];
        float s = sn + sdst[(size_t)c * H + head];
        s = (s > 0.f) ? s : 0.2f * s;
        float ae = __expf(fminf(s * we, 60.f));          // bitwise-identical to denom_k's term
        float w = ae / (denom[(size_t)c * H + head] + 1e-16f);   // <= 1 by construction
        const unsigned short* hp = hb + (size_t)c * D + lane * CPL;
        if constexpr (CPL == 4) {
            ushort4 hv = *(const ushort4*)hp;
            acc[0] += w * u2f(hv.x);
            acc[1] += w * u2f(hv.y);
            acc[2] += w * u2f(hv.z);
            acc[3] += w * u2f(hv.w);
        } else {
            unsigned int hv = *(const unsigned int*)hp;
            acc[0] += w * u2f((unsigned short)(hv & 0xFFFFu));
            acc[1] += w * u2f((unsigned short)(hv >> 16));
        }
    }
    float v[CPL];
    float sum = 0.f, sq = 0.f;
#pragma unroll
    for (int i = 0; i < CPL; i++) {
        v[i] = acc[i] + bias[lane * CPL + i];
        sum += v[i];
        sq += v[i] * v[i];
    }
#pragma unroll
    for (int m = 1; m < 64; m <<= 1) {
        sum += __shfl_xor(sum, m);
        sq += __shfl_xor(sq, m);
    }
    float mu  = sum * (1.0f / D);
    float var = sq * (1.0f / D) - mu * mu;
    float inv = rsqrtf(fmaxf(var, 0.f) + 1e-5f);
#pragma unroll
    for (int i = 0; i < CPL; i++) {
        float y = (v[i] - mu) * inv * gamma[lane * CPL + i] + beta[lane * CPL + i];
        if (DOELU) y = (y > 0.f) ? y : (__expf(y) - 1.f);
        size_t idx = (size_t)node * D + lane * CPL + i;
        if constexpr (F32OUT) ((float*)outv)[idx] = y;
        else                  ((unsigned short*)outv)[idx] = f2u(y);
    }
}

extern "C" void kernel_launch(void* const* d_in, const int* in_sizes, int n_in,
                              void* d_out, int out_size, void* d_ws, size_t ws_size,
                              hipStream_t stream) {
    const int IN_DIM = 384;
    const int N = in_sizes[0] / IN_DIM;
    const int E = in_sizes[1] / 2;
    float* outp = (float*)d_out;
    const int FG = 2048;

    if (n_in != 21 || out_size != N * 128) {           // arg mismatch -> 9.0 everywhere
        fill_const_f32_k<<<FG, 256, 0, stream>>>(outp, (long)out_size, 9.0f);
        return;
    }

    const float* x = (const float*)d_in[0];
    const int* ei = (const int*)d_in[1];
    const int* row = ei;
    const int* col = ei + E;
    const float* ew = (const float*)d_in[2];
    const float* W1 = (const float*)d_in[3];
    const float* as1 = (const float*)d_in[4];
    const float* ad1 = (const float*)d_in[5];
    const float* b1 = (const float*)d_in[6];
    const float* g1 = (const float*)d_in[7];
    const float* be1 = (const float*)d_in[8];
    const float* W2 = (const float*)d_in[9];
    const float* as2 = (const float*)d_in[10];
    const float* ad2 = (const float*)d_in[11];
    const float* b2 = (const float*)d_in[12];
    const float* g2 = (const float*)d_in[13];
    const float* be2 = (const float*)d_in[14];
    const float* W3 = (const float*)d_in[15];
    const float* as3 = (const float*)d_in[16];
    const float* ad3 = (const float*)d_in[17];
    const float* b3 = (const float*)d_in[18];
    const float* g3 = (const float*)d_in[19];
    const float* be3 = (const float*)d_in[20];

    char* ws = (char*)d_ws;
    size_t off = 0;
    auto alloc = [&](size_t b) -> char* {
        char* p = ws + off;
        off = (off + b + 255) & ~(size_t)255;
        return p;
    };
    unsigned short* xb = (unsigned short*)alloc((size_t)N * IN_DIM * 2);  // x in bf16
    unsigned short* hb = (unsigned short*)alloc((size_t)N * 256 * 2);     // GEMM out (bf16)
    unsigned short* ab = (unsigned short*)alloc((size_t)N * 256 * 2);     // activations (bf16)
    float* denom = (float*)alloc((size_t)N * 4 * 4);
    float* ssrc = (float*)alloc((size_t)N * 4 * 4);
    float* sdst = (float*)alloc((size_t)N * 4 * 4);
    unsigned short* W1t = (unsigned short*)alloc((size_t)384 * 256 * 2);
    unsigned short* W2t = (unsigned short*)alloc((size_t)256 * 256 * 2);
    unsigned short* W3t = (unsigned short*)alloc((size_t)256 * 128 * 2);
    int* rowptr = (int*)alloc((size_t)(N + 1) * 4);
    int* cnt = (int*)alloc((size_t)N * 4);
    int* cursor = (int*)alloc((size_t)N * 4);
    int* ccol = (int*)alloc((size_t)E * 4);
    float* cew = (float*)alloc((size_t)E * 4);

    if (off > ws_size) {                                // ws too small -> 7.0 everywhere
        fill_const_f32_k<<<FG, 256, 0, stream>>>(outp, (long)out_size, 7.0f);
        return;
    }

    const int ebl = (E + 255) / 256;
    const int nbl4 = (N + 3) / 4;
    const int mrows = (N + 127) / 128;

    // ---- input conversions ----
    f32_to_bf16_k<<<FG, 256, 0, stream>>>(x, xb, (long)N * IN_DIM);
    transpose_conv_k<<<(384 * 256 + 255) / 256, 256, 0, stream>>>(W1, W1t, 384, 256);
    transpose_conv_k<<<(256 * 256 + 255) / 256, 256, 0, stream>>>(W2, W2t, 256, 256);
    transpose_conv_k<<<(256 * 128 + 255) / 256, 256, 0, stream>>>(W3, W3t, 256, 128);

    // ---- CSR by row (shared by all 3 layers) ----
    hipMemsetAsync(cnt, 0, (size_t)N * 4, stream);
    count_k<<<ebl, 256, 0, stream>>>(row, cnt, E, N);
    exscan_k<<<1, 1024, 0, stream>>>(cnt, rowptr, cursor, N);
    fill_k<<<ebl, 256, 0, stream>>>(row, col, ew, cursor, ccol, cew, E, N);

    // ---- layer 1: 384 -> 4x64 concat ----
    gemm_bf16<<<dim3(2, mrows), 256, 0, stream>>>(xb, W1t, hb, N, 256, 384);
    scores_k<4, 16, 4><<<nbl4, 256, 0, stream>>>(hb, as1, ad1, ssrc, sdst, N);
    hipMemsetAsync(denom, 0, (size_t)N * 4 * 4, stream);
    denom_k<4><<<ebl, 256, 0, stream>>>(row, col, ew, ssrc, sdst, denom, E, N);
    agg_ln_k<4, 4, true, false><<<nbl4, 256, 0, stream>>>(hb, ssrc, sdst, denom, rowptr, ccol,
                                                          cew, b1, g1, be1, ab, N, E);

    // ---- layer 2: 256 -> 4x64 concat ----
    gemm_bf16<<<dim3(2, mrows), 256, 0, stream>>>(ab, W2t, hb, N, 256, 256);
    scores_k<4, 16, 4><<<nbl4, 256, 0, stream>>>(hb, as2, ad2, ssrc, sdst, N);
    hipMemsetAsync(denom, 0, (size_t)N * 4 * 4, stream);
    denom_k<4><<<ebl, 256, 0, stream>>>(row, col, ew, ssrc, sdst, denom, E, N);
    agg_ln_k<4, 4, true, false><<<nbl4, 256, 0, stream>>>(hb, ssrc, sdst, denom, rowptr, ccol,
                                                          cew, b2, g2, be2, ab, N, E);

    // ---- layer 3: 256 -> 128, single head, final LN (no ELU), fp32 out ----
    gemm_bf16<<<dim3(1, mrows), 256, 0, stream>>>(ab, W3t, hb, N, 128, 256);
    scores_k<2, 64, 1><<<nbl4, 256, 0, stream>>>(hb, as3, ad3, ssrc, sdst, N);
    hipMemsetAsync(denom, 0, (size_t)N * 4, stream);
    denom_k<1><<<ebl, 256, 0, stream>>>(row, col, ew, ssrc, sdst, denom, E, N);
    agg_ln_k<2, 1, false, true><<<nbl4, 256, 0, stream>>>(hb, ssrc, sdst, denom, rowptr, ccol,
                                                          cew, b3, g3, be3, outp, N, E);
}

// Round 6
// 714.940 us; speedup vs baseline: 1.2169x; 1.2169x over previous
//
#include <hip/hip_runtime.h>
#include <hip/hip_bf16.h>

// GAT 3-layer pipeline. fp32 I/O; bf16 MFMA interior.
// R6: denominator via CSC gather (no fp atomics), fused CSR+CSC build, fast scan.

typedef __bf16 bf16x8_t __attribute__((ext_vector_type(8)));
typedef float  fx4      __attribute__((ext_vector_type(4)));

__device__ __forceinline__ float u2f(unsigned short u) {
    return __uint_as_float(((unsigned)u) << 16);
}
__device__ __forceinline__ unsigned short f2u(float f) {
    unsigned b = __float_as_uint(f);
    unsigned rounded = b + 0x7FFF + ((b >> 16) & 1);
    if (((b >> 23) & 0xFF) == 0xFF) rounded = b;
    return (unsigned short)(rounded >> 16);
}

// ---------------- fp32 -> bf16 bulk convert ----------------
__global__ void f32_to_bf16_k(const float* __restrict__ src, unsigned short* __restrict__ dst,
                              long n) {
    long i = (long)blockIdx.x * 256 + threadIdx.x;
    const long stride = (long)gridDim.x * 256;
    for (; i < n; i += stride) dst[i] = f2u(src[i]);
}

__global__ void transpose_conv_k(const float* __restrict__ W, unsigned short* __restrict__ Wt,
                                 int K, int N) {
    int idx = blockIdx.x * 256 + threadIdx.x;
    if (idx >= K * N) return;
    int k = idx / N, n = idx - k * N;
    Wt[(size_t)n * K + k] = f2u(W[idx]);
}

__global__ void fill_const_f32_k(float* __restrict__ out, long n, float v) {
    long i = (long)blockIdx.x * 256 + threadIdx.x;
    const long stride = (long)gridDim.x * 256;
    for (; i < n; i += stride) out[i] = v;
}

// ---------------- combined CSR(by row) + CSC(by col) build ----------------
__global__ void count_both_k(const int* __restrict__ row, const int* __restrict__ col,
                             int* __restrict__ rcnt, int* __restrict__ ccnt, int E, int Nn) {
    int e = blockIdx.x * 256 + threadIdx.x;
    if (e >= E) return;
    int r = row[e], c = col[e];
    if ((unsigned)r < (unsigned)Nn) atomicAdd(&rcnt[r], 1);
    if ((unsigned)c < (unsigned)Nn) atomicAdd(&ccnt[c], 1);
}

// two independent exclusive scans (block 0: row arrays, block 1: col arrays).
// per-thread chunking: one block-scan of 1024 partials instead of 49 chunk-scans.
__global__ void exscan2_k(const int* __restrict__ cntA, int* __restrict__ ptrA, int* __restrict__ curA,
                          const int* __restrict__ cntB, int* __restrict__ ptrB, int* __restrict__ curB,
                          int N) {
    const int* cnt = blockIdx.x ? cntB : cntA;
    int* ptr = blockIdx.x ? ptrB : ptrA;
    int* cur = blockIdx.x ? curB : curA;
    const int T = 1024;
    __shared__ int sm[T];
    int tid = threadIdx.x;
    int C = (N + T - 1) / T;
    int beg = tid * C;
    int end = beg + C; if (end > N) end = N;
    int local = 0;
    for (int i = beg; i < end; i++) local += cnt[i];
    sm[tid] = local;
    __syncthreads();
    for (int o = 1; o < T; o <<= 1) {
        int t = (tid >= o) ? sm[tid - o] : 0;
        __syncthreads();
        sm[tid] += t;
        __syncthreads();
    }
    int run = (tid ? sm[tid - 1] : 0);
    if (tid == 0) ptr[0] = 0;
    for (int i = beg; i < end; i++) {
        cur[i] = run;
        run += cnt[i];
        ptr[i + 1] = run;
    }
}

__global__ void fill_both_k(const int* __restrict__ row, const int* __restrict__ col,
                            const float* __restrict__ ew,
                            int* __restrict__ rcur, int* __restrict__ ccur,
                            int* __restrict__ ccol, float* __restrict__ cewr,
                            int* __restrict__ crow, float* __restrict__ cewc,
                            int E, int Nn) {
    int e = blockIdx.x * 256 + threadIdx.x;
    if (e >= E) return;
    int r = row[e], c = col[e];
    float w = ew[e];
    if ((unsigned)r < (unsigned)Nn) {
        int s = atomicAdd(&rcur[r], 1);
        ccol[s] = ((unsigned)c < (unsigned)Nn) ? c : 0;
        cewr[s] = w;
    }
    if ((unsigned)c < (unsigned)Nn) {
        int s = atomicAdd(&ccur[c], 1);
        crow[s] = ((unsigned)r < (unsigned)Nn) ? r : 0;
        cewc[s] = w;
    }
}

// ---------------- bf16 MFMA GEMM: C[M,Ncol] = A[M,K] * Bt[Ncol,K]^T, bf16 out ----------------
#define LSTR 40
__global__ __launch_bounds__(256) void gemm_bf16(const unsigned short* __restrict__ A,
                                                 const unsigned short* __restrict__ Bt,
                                                 unsigned short* __restrict__ C,
                                                 int M, int Ncol, int K) {
    __shared__ unsigned short As[128 * LSTR];
    __shared__ unsigned short Bs[128 * LSTR];
    const int t = threadIdx.x;
    const int lane = t & 63;
    const int wave = t >> 6;
    const int quad = lane >> 4, l16 = lane & 15;
    const int row0 = blockIdx.y * 128, col0 = blockIdx.x * 128;
    const int wr = (wave >> 1) * 64, wc = (wave & 1) * 64;
    const int sr = t >> 2, ss = (t & 3) * 8;
    fx4 acc[4][4] = {};
    for (int k0 = 0; k0 < K; k0 += 32) {
#pragma unroll
        for (int rr = 0; rr < 2; rr++) {
            int r = sr + rr * 64;
            uint4 av = make_uint4(0, 0, 0, 0);
            int gr = row0 + r;
            if (gr < M) av = *(const uint4*)(A + (size_t)gr * K + k0 + ss);
            *(uint4*)(As + r * LSTR + ss) = av;
            uint4 bv = *(const uint4*)(Bt + (size_t)(col0 + r) * K + k0 + ss);
            *(uint4*)(Bs + r * LSTR + ss) = bv;
        }
        __syncthreads();
        bf16x8_t af[4], bfr[4];
#pragma unroll
        for (int i = 0; i < 4; i++) {
            af[i]  = *(const bf16x8_t*)(As + (wr + i * 16 + l16) * LSTR + quad * 8);
            bfr[i] = *(const bf16x8_t*)(Bs + (wc + i * 16 + l16) * LSTR + quad * 8);
        }
#pragma unroll
        for (int i = 0; i < 4; i++)
#pragma unroll
            for (int j = 0; j < 4; j++)
                acc[i][j] = __builtin_amdgcn_mfma_f32_16x16x32_bf16(af[i], bfr[j], acc[i][j], 0, 0, 0);
        __syncthreads();
    }
#pragma unroll
    for (int i = 0; i < 4; i++) {
        int rb = row0 + wr + i * 16 + quad * 4;
#pragma unroll
        for (int j = 0; j < 4; j++) {
            int c = col0 + wc + j * 16 + l16;
#pragma unroll
            for (int r = 0; r < 4; r++) {
                int gr = rb + r;
                if (gr < M) C[(size_t)gr * Ncol + c] = f2u(acc[i][j][r]);
            }
        }
    }
}

// ---------------- per-node attention scores (fp32 params, bf16 h) ----------------
template <int CPL, int LPH, int H>
__global__ __launch_bounds__(256) void scores_k(const unsigned short* __restrict__ hb,
                                                const float* __restrict__ asrc,
                                                const float* __restrict__ adst,
                                                float* __restrict__ ssrc, float* __restrict__ sdst,
                                                int N) {
    int node = blockIdx.x * 4 + (threadIdx.x >> 6);
    if (node >= N) return;
    int lane = threadIdx.x & 63;
    const int D = CPL * 64;
    const unsigned short* hp = hb + (size_t)node * D + lane * CPL;
    float s1 = 0.f, s2 = 0.f;
#pragma unroll
    for (int i = 0; i < CPL; i++) {
        float h = u2f(hp[i]);
        s1 += h * asrc[lane * CPL + i];
        s2 += h * adst[lane * CPL + i];
    }
#pragma unroll
    for (int m = 1; m < LPH; m <<= 1) {
        s1 += __shfl_xor(s1, m);
        s2 += __shfl_xor(s2, m);
    }
    if ((lane & (LPH - 1)) == 0) {
        ssrc[(size_t)node * H + lane / LPH] = s1;
        sdst[(size_t)node * H + lane / LPH] = s2;
    }
}

// ---------------- softmax denominator via CSC gather (no atomics) ----------------
// H lanes per node (one per head); reads ssrc[r*H+h] coalesced across the H lanes.
template <int H>
__global__ __launch_bounds__(256) void denom_csc_k(const int* __restrict__ colptr,
                                                   const int* __restrict__ crow,
                                                   const float* __restrict__ cewc,
                                                   const float* __restrict__ ssrc,
                                                   const float* __restrict__ sdst,
                                                   float* __restrict__ denom, int N) {
    int idx = blockIdx.x * 256 + threadIdx.x;
    int node = idx / H;
    int h = idx - node * H;
    if (node >= N) return;
    const float sd = sdst[(size_t)node * H + h];
    float acc = 0.f;
    int kbeg = colptr[node], kend = colptr[node + 1];
    for (int k = kbeg; k < kend; k++) {
        int r = crow[k];
        float we = cewc[k];
        float s = ssrc[(size_t)r * H + h] + sd;
        s = (s > 0.f) ? s : 0.2f * s;                 // leaky_relu 0.2
        acc += __expf(fminf(s * we, 60.f));
    }
    denom[(size_t)node * H + h] = acc;
}

// ---------------- fused: CSR aggregate (recomputed alpha) + bias + LN + (ELU) ----------------
template <int CPL, int H, bool DOELU, bool F32OUT>
__global__ __launch_bounds__(256) void agg_ln_k(const unsigned short* __restrict__ hb,
                                                const float* __restrict__ ssrc,
                                                const float* __restrict__ sdst,
                                                const float* __restrict__ denom,
                                                const int* __restrict__ rowptr,
                                                const int* __restrict__ ccol,
                                                const float* __restrict__ cew,
                                                const float* __restrict__ bias,
                                                const float* __restrict__ gamma,
                                                const float* __restrict__ beta,
                                                void* __restrict__ outv, int N, int E) {
    int node = blockIdx.x * 4 + (threadIdx.x >> 6);
    if (node >= N) return;
    int lane = threadIdx.x & 63;
    const int D = CPL * 64, C = D / H;
    const int head = (lane * CPL) / C;
    const float sn = ssrc[(size_t)node * H + head];
    float acc[CPL] = {};
    int kbeg = rowptr[node], kend = rowptr[node + 1];
    if (kbeg < 0) kbeg = 0;
    if (kend > E) kend = E;
    for (int k = kbeg; k < kend; k++) {
        int c = ccol[k];
        float we = cew[k];
        float s = sn + sdst[(size_t)c * H + head];
        s = (s > 0.f) ? s : 0.2f * s;
        float ae = __expf(fminf(s * we, 60.f));       // bitwise-identical to denom term
        float w = ae / (denom[(size_t)c * H + head] + 1e-16f);
        const unsigned short* hp = hb + (size_t)c * D + lane * CPL;
        if constexpr (CPL == 4) {
            ushort4 hv = *(const ushort4*)hp;
            acc[0] += w * u2f(hv.x);
            acc[1] += w * u2f(hv.y);
            acc[2] += w * u2f(hv.z);
            acc[3] += w * u2f(hv.w);
        } else {
            unsigned int hv = *(const unsigned int*)hp;
            acc[0] += w * u2f((unsigned short)(hv & 0xFFFFu));
            acc[1] += w * u2f((unsigned short)(hv >> 16));
        }
    }
    float v[CPL];
    float sum = 0.f, sq = 0.f;
#pragma unroll
    for (int i = 0; i < CPL; i++) {
        v[i] = acc[i] + bias[lane * CPL + i];
        sum += v[i];
        sq += v[i] * v[i];
    }
#pragma unroll
    for (int m = 1; m < 64; m <<= 1) {
        sum += __shfl_xor(sum, m);
        sq += __shfl_xor(sq, m);
    }
    float mu  = sum * (1.0f / D);
    float var = sq * (1.0f / D) - mu * mu;
    float inv = rsqrtf(fmaxf(var, 0.f) + 1e-5f);
#pragma unroll
    for (int i = 0; i < CPL; i++) {
        float y = (v[i] - mu) * inv * gamma[lane * CPL + i] + beta[lane * CPL + i];
        if (DOELU) y = (y > 0.f) ? y : (__expf(y) - 1.f);
        size_t idx = (size_t)node * D + lane * CPL + i;
        if constexpr (F32OUT) ((float*)outv)[idx] = y;
        else                  ((unsigned short*)outv)[idx] = f2u(y);
    }
}

extern "C" void kernel_launch(void* const* d_in, const int* in_sizes, int n_in,
                              void* d_out, int out_size, void* d_ws, size_t ws_size,
                              hipStream_t stream) {
    const int IN_DIM = 384;
    const int N = in_sizes[0] / IN_DIM;
    const int E = in_sizes[1] / 2;
    float* outp = (float*)d_out;
    const int FG = 2048;

    if (n_in != 21 || out_size != N * 128) {
        fill_const_f32_k<<<FG, 256, 0, stream>>>(outp, (long)out_size, 9.0f);
        return;
    }

    const float* x = (const float*)d_in[0];
    const int* ei = (const int*)d_in[1];
    const int* row = ei;
    const int* col = ei + E;
    const float* ew = (const float*)d_in[2];
    const float* W1 = (const float*)d_in[3];
    const float* as1 = (const float*)d_in[4];
    const float* ad1 = (const float*)d_in[5];
    const float* b1 = (const float*)d_in[6];
    const float* g1 = (const float*)d_in[7];
    const float* be1 = (const float*)d_in[8];
    const float* W2 = (const float*)d_in[9];
    const float* as2 = (const float*)d_in[10];
    const float* ad2 = (const float*)d_in[11];
    const float* b2 = (const float*)d_in[12];
    const float* g2 = (const float*)d_in[13];
    const float* be2 = (const float*)d_in[14];
    const float* W3 = (const float*)d_in[15];
    const float* as3 = (const float*)d_in[16];
    const float* ad3 = (const float*)d_in[17];
    const float* b3 = (const float*)d_in[18];
    const float* g3 = (const float*)d_in[19];
    const float* be3 = (const float*)d_in[20];

    char* ws = (char*)d_ws;
    size_t off = 0;
    auto alloc = [&](size_t b) -> char* {
        char* p = ws + off;
        off = (off + b + 255) & ~(size_t)255;
        return p;
    };
    unsigned short* xb = (unsigned short*)alloc((size_t)N * IN_DIM * 2);
    unsigned short* hb = (unsigned short*)alloc((size_t)N * 256 * 2);
    unsigned short* ab = (unsigned short*)alloc((size_t)N * 256 * 2);
    float* denom = (float*)alloc((size_t)N * 4 * 4);
    float* ssrc = (float*)alloc((size_t)N * 4 * 4);
    float* sdst = (float*)alloc((size_t)N * 4 * 4);
    unsigned short* W1t = (unsigned short*)alloc((size_t)384 * 256 * 2);
    unsigned short* W2t = (unsigned short*)alloc((size_t)256 * 256 * 2);
    unsigned short* W3t = (unsigned short*)alloc((size_t)256 * 128 * 2);
    int* rowptr = (int*)alloc((size_t)(N + 1) * 4);
    int* colptr = (int*)alloc((size_t)(N + 1) * 4);
    int* cnt2 = (int*)alloc((size_t)2 * N * 4);      // [rcnt | ccnt]
    int* rcur = (int*)alloc((size_t)N * 4);
    int* ccur = (int*)alloc((size_t)N * 4);
    int* ccol = (int*)alloc((size_t)E * 4);          // CSR: col per slot
    float* cewr = (float*)alloc((size_t)E * 4);      // CSR: ew per slot
    int* crow = (int*)alloc((size_t)E * 4);          // CSC: row per slot
    float* cewc = (float*)alloc((size_t)E * 4);      // CSC: ew per slot

    if (off > ws_size) {
        fill_const_f32_k<<<FG, 256, 0, stream>>>(outp, (long)out_size, 7.0f);
        return;
    }

    int* rcnt = cnt2;
    int* ccnt = cnt2 + N;

    const int ebl = (E + 255) / 256;
    const int nbl4 = (N + 3) / 4;
    const int mrows = (N + 127) / 128;

    // ---- input conversions ----
    f32_to_bf16_k<<<FG, 256, 0, stream>>>(x, xb, (long)N * IN_DIM);
    transpose_conv_k<<<(384 * 256 + 255) / 256, 256, 0, stream>>>(W1, W1t, 384, 256);
    transpose_conv_k<<<(256 * 256 + 255) / 256, 256, 0, stream>>>(W2, W2t, 256, 256);
    transpose_conv_k<<<(256 * 128 + 255) / 256, 256, 0, stream>>>(W3, W3t, 256, 128);

    // ---- CSR + CSC build (once, shared by all layers) ----
    hipMemsetAsync(cnt2, 0, (size_t)2 * N * 4, stream);
    count_both_k<<<ebl, 256, 0, stream>>>(row, col, rcnt, ccnt, E, N);
    exscan2_k<<<2, 1024, 0, stream>>>(rcnt, rowptr, rcur, ccnt, colptr, ccur, N);
    fill_both_k<<<ebl, 256, 0, stream>>>(row, col, ew, rcur, ccur,
                                         ccol, cewr, crow, cewc, E, N);

    // ---- layer 1: 384 -> 4x64 concat ----
    gemm_bf16<<<dim3(2, mrows), 256, 0, stream>>>(xb, W1t, hb, N, 256, 384);
    scores_k<4, 16, 4><<<nbl4, 256, 0, stream>>>(hb, as1, ad1, ssrc, sdst, N);
    denom_csc_k<4><<<(N * 4 + 255) / 256, 256, 0, stream>>>(colptr, crow, cewc, ssrc, sdst, denom, N);
    agg_ln_k<4, 4, true, false><<<nbl4, 256, 0, stream>>>(hb, ssrc, sdst, denom, rowptr, ccol,
                                                          cewr, b1, g1, be1, ab, N, E);

    // ---- layer 2: 256 -> 4x64 concat ----
    gemm_bf16<<<dim3(2, mrows), 256, 0, stream>>>(ab, W2t, hb, N, 256, 256);
    scores_k<4, 16, 4><<<nbl4, 256, 0, stream>>>(hb, as2, ad2, ssrc, sdst, N);
    denom_csc_k<4><<<(N * 4 + 255) / 256, 256, 0, stream>>>(colptr, crow, cewc, ssrc, sdst, denom, N);
    agg_ln_k<4, 4, true, false><<<nbl4, 256, 0, stream>>>(hb, ssrc, sdst, denom, rowptr, ccol,
                                                          cewr, b2, g2, be2, ab, N, E);

    // ---- layer 3: 256 -> 128, single head, final LN (no ELU), fp32 out ----
    gemm_bf16<<<dim3(1, mrows), 256, 0, stream>>>(ab, W3t, hb, N, 128, 256);
    scores_k<2, 64, 1><<<nbl4, 256, 0, stream>>>(hb, as3, ad3, ssrc, sdst, N);
    denom_csc_k<1><<<(N + 255) / 256, 256, 0, stream>>>(colptr, crow, cewc, ssrc, sdst, denom, N);
    agg_ln_k<2, 1, false, true><<<nbl4, 256, 0, stream>>>(hb, ssrc, sdst, denom, rowptr, ccol,
                                                          cewr, b3, g3, be3, outp, N, E);
}

// Round 7
// 618.515 us; speedup vs baseline: 1.4066x; 1.1559x over previous
//
#include <hip/hip_runtime.h>
#include <hip/hip_bf16.h>

// GAT 3-layer pipeline. fp32 I/O; bf16 MFMA interior.
// R7: replace 2-block serial exscan (110us, 0.27% occ) with 3-pass device-wide scan.

typedef __bf16 bf16x8_t __attribute__((ext_vector_type(8)));
typedef float  fx4      __attribute__((ext_vector_type(4)));

__device__ __forceinline__ float u2f(unsigned short u) {
    return __uint_as_float(((unsigned)u) << 16);
}
__device__ __forceinline__ unsigned short f2u(float f) {
    unsigned b = __float_as_uint(f);
    unsigned rounded = b + 0x7FFF + ((b >> 16) & 1);
    if (((b >> 23) & 0xFF) == 0xFF) rounded = b;
    return (unsigned short)(rounded >> 16);
}

// ---------------- fp32 -> bf16 bulk convert ----------------
__global__ void f32_to_bf16_k(const float* __restrict__ src, unsigned short* __restrict__ dst,
                              long n) {
    long i = (long)blockIdx.x * 256 + threadIdx.x;
    const long stride = (long)gridDim.x * 256;
    for (; i < n; i += stride) dst[i] = f2u(src[i]);
}

__global__ void transpose_conv_k(const float* __restrict__ W, unsigned short* __restrict__ Wt,
                                 int K, int N) {
    int idx = blockIdx.x * 256 + threadIdx.x;
    if (idx >= K * N) return;
    int k = idx / N, n = idx - k * N;
    Wt[(size_t)n * K + k] = f2u(W[idx]);
}

__global__ void fill_const_f32_k(float* __restrict__ out, long n, float v) {
    long i = (long)blockIdx.x * 256 + threadIdx.x;
    const long stride = (long)gridDim.x * 256;
    for (; i < n; i += stride) out[i] = v;
}

// ---------------- combined CSR(by row) + CSC(by col) build ----------------
__global__ void count_both_k(const int* __restrict__ row, const int* __restrict__ col,
                             int* __restrict__ rcnt, int* __restrict__ ccnt, int E, int Nn) {
    int e = blockIdx.x * 256 + threadIdx.x;
    if (e >= E) return;
    int r = row[e], c = col[e];
    if ((unsigned)r < (unsigned)Nn) atomicAdd(&rcnt[r], 1);
    if ((unsigned)c < (unsigned)Nn) atomicAdd(&ccnt[c], 1);
}

// ---- 3-pass device-wide inclusive scan over cnt2[0..2N) = [rcnt | ccnt] ----
// pass 1: block-local inclusive scan + per-block sums
__global__ __launch_bounds__(256) void scan1_k(const int* __restrict__ cnt,
                                               int* __restrict__ local,
                                               int* __restrict__ bsum, int n) {
    __shared__ int sm[256];
    int i = blockIdx.x * 256 + threadIdx.x;
    int tid = threadIdx.x;
    int v = (i < n) ? cnt[i] : 0;
    sm[tid] = v;
    __syncthreads();
    for (int o = 1; o < 256; o <<= 1) {
        int t = (tid >= o) ? sm[tid - o] : 0;
        __syncthreads();
        sm[tid] += t;
        __syncthreads();
    }
    if (i < n) local[i] = sm[tid];
    if (tid == 255) bsum[blockIdx.x] = sm[255];
}

// pass 2: single block scans block sums (nb <= 512)
__global__ __launch_bounds__(512) void scan2_k(int* __restrict__ bsum, int nb) {
    __shared__ int sm[512];
    int tid = threadIdx.x;
    int v = (tid < nb) ? bsum[tid] : 0;
    sm[tid] = v;
    __syncthreads();
    for (int o = 1; o < 512; o <<= 1) {
        int t = (tid >= o) ? sm[tid - o] : 0;
        __syncthreads();
        sm[tid] += t;
        __syncthreads();
    }
    if (tid < nb) bsum[tid] = sm[tid];
}

// pass 3: global inclusive value S[i] = local[i] + bsum[b-1]; derive ptr/cur arrays.
// first half (i<N): rowptr/rcur; second half: colptr/ccur with base = S[N-1].
__global__ __launch_bounds__(256) void scan3_k(const int* __restrict__ cnt,
                                               const int* __restrict__ local,
                                               const int* __restrict__ bsum,
                                               int* __restrict__ rowptr, int* __restrict__ rcur,
                                               int* __restrict__ colptr, int* __restrict__ ccur,
                                               int N) {
    int i = blockIdx.x * 256 + threadIdx.x;
    int n2 = 2 * N;
    if (i >= n2) return;
    int b = blockIdx.x;
    int s = local[i] + (b > 0 ? bsum[b - 1] : 0);
    int v = cnt[i];
    if (i < N) {
        rowptr[i + 1] = s;
        rcur[i] = s - v;
        if (i == 0) rowptr[0] = 0;
    } else {
        int bN = (N - 1) >> 8;
        int base = local[N - 1] + (bN > 0 ? bsum[bN - 1] : 0);   // broadcast loads
        int j = i - N;
        colptr[j + 1] = s - base;
        ccur[j] = s - v - base;
        if (j == 0) colptr[0] = 0;
    }
}

__global__ void fill_both_k(const int* __restrict__ row, const int* __restrict__ col,
                            const float* __restrict__ ew,
                            int* __restrict__ rcur, int* __restrict__ ccur,
                            int* __restrict__ ccol, float* __restrict__ cewr,
                            int* __restrict__ crow, float* __restrict__ cewc,
                            int E, int Nn) {
    int e = blockIdx.x * 256 + threadIdx.x;
    if (e >= E) return;
    int r = row[e], c = col[e];
    float w = ew[e];
    if ((unsigned)r < (unsigned)Nn) {
        int s = atomicAdd(&rcur[r], 1);
        ccol[s] = ((unsigned)c < (unsigned)Nn) ? c : 0;
        cewr[s] = w;
    }
    if ((unsigned)c < (unsigned)Nn) {
        int s = atomicAdd(&ccur[c], 1);
        crow[s] = ((unsigned)r < (unsigned)Nn) ? r : 0;
        cewc[s] = w;
    }
}

// ---------------- bf16 MFMA GEMM: C[M,Ncol] = A[M,K] * Bt[Ncol,K]^T, bf16 out ----------------
#define LSTR 40
__global__ __launch_bounds__(256) void gemm_bf16(const unsigned short* __restrict__ A,
                                                 const unsigned short* __restrict__ Bt,
                                                 unsigned short* __restrict__ C,
                                                 int M, int Ncol, int K) {
    __shared__ unsigned short As[128 * LSTR];
    __shared__ unsigned short Bs[128 * LSTR];
    const int t = threadIdx.x;
    const int lane = t & 63;
    const int wave = t >> 6;
    const int quad = lane >> 4, l16 = lane & 15;
    const int row0 = blockIdx.y * 128, col0 = blockIdx.x * 128;
    const int wr = (wave >> 1) * 64, wc = (wave & 1) * 64;
    const int sr = t >> 2, ss = (t & 3) * 8;
    fx4 acc[4][4] = {};
    for (int k0 = 0; k0 < K; k0 += 32) {
#pragma unroll
        for (int rr = 0; rr < 2; rr++) {
            int r = sr + rr * 64;
            uint4 av = make_uint4(0, 0, 0, 0);
            int gr = row0 + r;
            if (gr < M) av = *(const uint4*)(A + (size_t)gr * K + k0 + ss);
            *(uint4*)(As + r * LSTR + ss) = av;
            uint4 bv = *(const uint4*)(Bt + (size_t)(col0 + r) * K + k0 + ss);
            *(uint4*)(Bs + r * LSTR + ss) = bv;
        }
        __syncthreads();
        bf16x8_t af[4], bfr[4];
#pragma unroll
        for (int i = 0; i < 4; i++) {
            af[i]  = *(const bf16x8_t*)(As + (wr + i * 16 + l16) * LSTR + quad * 8);
            bfr[i] = *(const bf16x8_t*)(Bs + (wc + i * 16 + l16) * LSTR + quad * 8);
        }
#pragma unroll
        for (int i = 0; i < 4; i++)
#pragma unroll
            for (int j = 0; j < 4; j++)
                acc[i][j] = __builtin_amdgcn_mfma_f32_16x16x32_bf16(af[i], bfr[j], acc[i][j], 0, 0, 0);
        __syncthreads();
    }
#pragma unroll
    for (int i = 0; i < 4; i++) {
        int rb = row0 + wr + i * 16 + quad * 4;
#pragma unroll
        for (int j = 0; j < 4; j++) {
            int c = col0 + wc + j * 16 + l16;
#pragma unroll
            for (int r = 0; r < 4; r++) {
                int gr = rb + r;
                if (gr < M) C[(size_t)gr * Ncol + c] = f2u(acc[i][j][r]);
            }
        }
    }
}

// ---------------- per-node attention scores (fp32 params, bf16 h) ----------------
template <int CPL, int LPH, int H>
__global__ __launch_bounds__(256) void scores_k(const unsigned short* __restrict__ hb,
                                                const float* __restrict__ asrc,
                                                const float* __restrict__ adst,
                                                float* __restrict__ ssrc, float* __restrict__ sdst,
                                                int N) {
    int node = blockIdx.x * 4 + (threadIdx.x >> 6);
    if (node >= N) return;
    int lane = threadIdx.x & 63;
    const int D = CPL * 64;
    const unsigned short* hp = hb + (size_t)node * D + lane * CPL;
    float s1 = 0.f, s2 = 0.f;
#pragma unroll
    for (int i = 0; i < CPL; i++) {
        float h = u2f(hp[i]);
        s1 += h * asrc[lane * CPL + i];
        s2 += h * adst[lane * CPL + i];
    }
#pragma unroll
    for (int m = 1; m < LPH; m <<= 1) {
        s1 += __shfl_xor(s1, m);
        s2 += __shfl_xor(s2, m);
    }
    if ((lane & (LPH - 1)) == 0) {
        ssrc[(size_t)node * H + lane / LPH] = s1;
        sdst[(size_t)node * H + lane / LPH] = s2;
    }
}

// ---------------- softmax denominator via CSC gather (no atomics) ----------------
template <int H>
__global__ __launch_bounds__(256) void denom_csc_k(const int* __restrict__ colptr,
                                                   const int* __restrict__ crow,
                                                   const float* __restrict__ cewc,
                                                   const float* __restrict__ ssrc,
                                                   const float* __restrict__ sdst,
                                                   float* __restrict__ denom, int N) {
    int idx = blockIdx.x * 256 + threadIdx.x;
    int node = idx / H;
    int h = idx - node * H;
    if (node >= N) return;
    const float sd = sdst[(size_t)node * H + h];
    float acc = 0.f;
    int kbeg = colptr[node], kend = colptr[node + 1];
    for (int k = kbeg; k < kend; k++) {
        int r = crow[k];
        float we = cewc[k];
        float s = ssrc[(size_t)r * H + h] + sd;
        s = (s > 0.f) ? s : 0.2f * s;                 // leaky_relu 0.2
        acc += __expf(fminf(s * we, 60.f));
    }
    denom[(size_t)node * H + h] = acc;
}

// ---------------- fused: CSR aggregate (recomputed alpha) + bias + LN + (ELU) ----------------
template <int CPL, int H, bool DOELU, bool F32OUT>
__global__ __launch_bounds__(256) void agg_ln_k(const unsigned short* __restrict__ hb,
                                                const float* __restrict__ ssrc,
                                                const float* __restrict__ sdst,
                                                const float* __restrict__ denom,
                                                const int* __restrict__ rowptr,
                                                const int* __restrict__ ccol,
                                                const float* __restrict__ cew,
                                                const float* __restrict__ bias,
                                                const float* __restrict__ gamma,
                                                const float* __restrict__ beta,
                                                void* __restrict__ outv, int N, int E) {
    int node = blockIdx.x * 4 + (threadIdx.x >> 6);
    if (node >= N) return;
    int lane = threadIdx.x & 63;
    const int D = CPL * 64, C = D / H;
    const int head = (lane * CPL) / C;
    const float sn = ssrc[(size_t)node * H + head];
    float acc[CPL] = {};
    int kbeg = rowptr[node], kend = rowptr[node + 1];
    if (kbeg < 0) kbeg = 0;
    if (kend > E) kend = E;
    for (int k = kbeg; k < kend; k++) {
        int c = ccol[k];
        float we = cew[k];
        float s = sn + sdst[(size_t)c * H + head];
        s = (s > 0.f) ? s : 0.2f * s;
        float ae = __expf(fminf(s * we, 60.f));       // bitwise-identical to denom term
        float w = ae / (denom[(size_t)c * H + head] + 1e-16f);
        const unsigned short* hp = hb + (size_t)c * D + lane * CPL;
        if constexpr (CPL == 4) {
            ushort4 hv = *(const ushort4*)hp;
            acc[0] += w * u2f(hv.x);
            acc[1] += w * u2f(hv.y);
            acc[2] += w * u2f(hv.z);
            acc[3] += w * u2f(hv.w);
        } else {
            unsigned int hv = *(const unsigned int*)hp;
            acc[0] += w * u2f((unsigned short)(hv & 0xFFFFu));
            acc[1] += w * u2f((unsigned short)(hv >> 16));
        }
    }
    float v[CPL];
    float sum = 0.f, sq = 0.f;
#pragma unroll
    for (int i = 0; i < CPL; i++) {
        v[i] = acc[i] + bias[lane * CPL + i];
        sum += v[i];
        sq += v[i] * v[i];
    }
#pragma unroll
    for (int m = 1; m < 64; m <<= 1) {
        sum += __shfl_xor(sum, m);
        sq += __shfl_xor(sq, m);
    }
    float mu  = sum * (1.0f / D);
    float var = sq * (1.0f / D) - mu * mu;
    float inv = rsqrtf(fmaxf(var, 0.f) + 1e-5f);
#pragma unroll
    for (int i = 0; i < CPL; i++) {
        float y = (v[i] - mu) * inv * gamma[lane * CPL + i] + beta[lane * CPL + i];
        if (DOELU) y = (y > 0.f) ? y : (__expf(y) - 1.f);
        size_t idx = (size_t)node * D + lane * CPL + i;
        if constexpr (F32OUT) ((float*)outv)[idx] = y;
        else                  ((unsigned short*)outv)[idx] = f2u(y);
    }
}

extern "C" void kernel_launch(void* const* d_in, const int* in_sizes, int n_in,
                              void* d_out, int out_size, void* d_ws, size_t ws_size,
                              hipStream_t stream) {
    const int IN_DIM = 384;
    const int N = in_sizes[0] / IN_DIM;
    const int E = in_sizes[1] / 2;
    float* outp = (float*)d_out;
    const int FG = 2048;

    if (n_in != 21 || out_size != N * 128) {
        fill_const_f32_k<<<FG, 256, 0, stream>>>(outp, (long)out_size, 9.0f);
        return;
    }

    const float* x = (const float*)d_in[0];
    const int* ei = (const int*)d_in[1];
    const int* row = ei;
    const int* col = ei + E;
    const float* ew = (const float*)d_in[2];
    const float* W1 = (const float*)d_in[3];
    const float* as1 = (const float*)d_in[4];
    const float* ad1 = (const float*)d_in[5];
    const float* b1 = (const float*)d_in[6];
    const float* g1 = (const float*)d_in[7];
    const float* be1 = (const float*)d_in[8];
    const float* W2 = (const float*)d_in[9];
    const float* as2 = (const float*)d_in[10];
    const float* ad2 = (const float*)d_in[11];
    const float* b2 = (const float*)d_in[12];
    const float* g2 = (const float*)d_in[13];
    const float* be2 = (const float*)d_in[14];
    const float* W3 = (const float*)d_in[15];
    const float* as3 = (const float*)d_in[16];
    const float* ad3 = (const float*)d_in[17];
    const float* b3 = (const float*)d_in[18];
    const float* g3 = (const float*)d_in[19];
    const float* be3 = (const float*)d_in[20];

    char* ws = (char*)d_ws;
    size_t off = 0;
    auto alloc = [&](size_t b) -> char* {
        char* p = ws + off;
        off = (off + b + 255) & ~(size_t)255;
        return p;
    };
    unsigned short* xb = (unsigned short*)alloc((size_t)N * IN_DIM * 2);
    unsigned short* hb = (unsigned short*)alloc((size_t)N * 256 * 2);
    unsigned short* ab = (unsigned short*)alloc((size_t)N * 256 * 2);
    float* denom = (float*)alloc((size_t)N * 4 * 4);
    float* ssrc = (float*)alloc((size_t)N * 4 * 4);
    float* sdst = (float*)alloc((size_t)N * 4 * 4);
    unsigned short* W1t = (unsigned short*)alloc((size_t)384 * 256 * 2);
    unsigned short* W2t = (unsigned short*)alloc((size_t)256 * 256 * 2);
    unsigned short* W3t = (unsigned short*)alloc((size_t)256 * 128 * 2);
    int* rowptr = (int*)alloc((size_t)(N + 1) * 4);
    int* colptr = (int*)alloc((size_t)(N + 1) * 4);
    int* cnt2 = (int*)alloc((size_t)2 * N * 4);      // [rcnt | ccnt]
    int* slocal = (int*)alloc((size_t)2 * N * 4);    // scan pass-1 local results
    int* sbsum = (int*)alloc((size_t)512 * 4);       // scan block sums
    int* rcur = (int*)alloc((size_t)N * 4);
    int* ccur = (int*)alloc((size_t)N * 4);
    int* ccol = (int*)alloc((size_t)E * 4);          // CSR: col per slot
    float* cewr = (float*)alloc((size_t)E * 4);      // CSR: ew per slot
    int* crow = (int*)alloc((size_t)E * 4);          // CSC: row per slot
    float* cewc = (float*)alloc((size_t)E * 4);      // CSC: ew per slot

    if (off > ws_size) {
        fill_const_f32_k<<<FG, 256, 0, stream>>>(outp, (long)out_size, 7.0f);
        return;
    }

    int* rcnt = cnt2;
    int* ccnt = cnt2 + N;

    const int ebl = (E + 255) / 256;
    const int nbl4 = (N + 3) / 4;
    const int mrows = (N + 127) / 128;
    const int n2 = 2 * N;
    const int sblocks = (n2 + 255) / 256;            // 391 for N=50000 (<=512)

    // ---- input conversions ----
    f32_to_bf16_k<<<FG, 256, 0, stream>>>(x, xb, (long)N * IN_DIM);
    transpose_conv_k<<<(384 * 256 + 255) / 256, 256, 0, stream>>>(W1, W1t, 384, 256);
    transpose_conv_k<<<(256 * 256 + 255) / 256, 256, 0, stream>>>(W2, W2t, 256, 256);
    transpose_conv_k<<<(256 * 128 + 255) / 256, 256, 0, stream>>>(W3, W3t, 256, 128);

    // ---- CSR + CSC build (once, shared by all layers) ----
    hipMemsetAsync(cnt2, 0, (size_t)n2 * 4, stream);
    count_both_k<<<ebl, 256, 0, stream>>>(row, col, rcnt, ccnt, E, N);
    scan1_k<<<sblocks, 256, 0, stream>>>(cnt2, slocal, sbsum, n2);
    scan2_k<<<1, 512, 0, stream>>>(sbsum, sblocks);
    scan3_k<<<sblocks, 256, 0, stream>>>(cnt2, slocal, sbsum, rowptr, rcur, colptr, ccur, N);
    fill_both_k<<<ebl, 256, 0, stream>>>(row, col, ew, rcur, ccur,
                                         ccol, cewr, crow, cewc, E, N);

    // ---- layer 1: 384 -> 4x64 concat ----
    gemm_bf16<<<dim3(2, mrows), 256, 0, stream>>>(xb, W1t, hb, N, 256, 384);
    scores_k<4, 16, 4><<<nbl4, 256, 0, stream>>>(hb, as1, ad1, ssrc, sdst, N);
    denom_csc_k<4><<<(N * 4 + 255) / 256, 256, 0, stream>>>(colptr, crow, cewc, ssrc, sdst, denom, N);
    agg_ln_k<4, 4, true, false><<<nbl4, 256, 0, stream>>>(hb, ssrc, sdst, denom, rowptr, ccol,
                                                          cewr, b1, g1, be1, ab, N, E);

    // ---- layer 2: 256 -> 4x64 concat ----
    gemm_bf16<<<dim3(2, mrows), 256, 0, stream>>>(ab, W2t, hb, N, 256, 256);
    scores_k<4, 16, 4><<<nbl4, 256, 0, stream>>>(hb, as2, ad2, ssrc, sdst, N);
    denom_csc_k<4><<<(N * 4 + 255) / 256, 256, 0, stream>>>(colptr, crow, cewc, ssrc, sdst, denom, N);
    agg_ln_k<4, 4, true, false><<<nbl4, 256, 0, stream>>>(hb, ssrc, sdst, denom, rowptr, ccol,
                                                          cewr, b2, g2, be2, ab, N, E);

    // ---- layer 3: 256 -> 128, single head, final LN (no ELU), fp32 out ----
    gemm_bf16<<<dim3(1, mrows), 256, 0, stream>>>(ab, W3t, hb, N, 128, 256);
    scores_k<2, 64, 1><<<nbl4, 256, 0, stream>>>(hb, as3, ad3, ssrc, sdst, N);
    denom_csc_k<1><<<(N + 255) / 256, 256, 0, stream>>>(colptr, crow, cewc, ssrc, sdst, denom, N);
    agg_ln_k<2, 1, false, true><<<nbl4, 256, 0, stream>>>(hb, ssrc, sdst, denom, rowptr, ccol,
                                                          cewr, b3, g3, be3, outp, N, E);
}